// Round 10
// baseline (182.443 us; speedup 1.0000x reference)
//
#include <hip/hip_runtime.h>
#include <math.h>

#define NCLASS 40
#define BSH    7        // bucket = dst>>7 (128 nodes/bucket)
#define BSIZE  128
#define MAXB   512      // max buckets; N=50000 -> 391 used
#define EPB    4096     // edges per block in bhist/bin (E<=1M -> nbin<=256)

typedef __attribute__((ext_vector_type(8))) short short8;   // 8 bf16 = 4 VGPRs
typedef __attribute__((ext_vector_type(4))) float float4v;  // MFMA 16x16 C/D

__device__ __forceinline__ unsigned short f2bf(float f) {
    union { float f; unsigned u; } v; v.f = f;
    unsigned r = v.u + 0x7fffu + ((v.u >> 16) & 1u);   // round-nearest-even
    return (unsigned short)(r >> 16);
}
__device__ __forceinline__ float bf2f(unsigned int s) {
    union { unsigned u; float f; } v; v.u = s << 16; return v.f;
}

// ---------------------------------------------------------------------------
// Merged: bhist (blocks [0,nbin)) + x->bf16 conv + W1/W2 frag-order conv.
// ---------------------------------------------------------------------------
__global__ __launch_bounds__(256) void convhist_kernel(const int* __restrict__ ei,
                                                       const float4* __restrict__ x4,
                                                       const float* __restrict__ W1l,
                                                       const float* __restrict__ W1r,
                                                       const float* __restrict__ W2l,
                                                       const float* __restrict__ W2r,
                                                       int* __restrict__ histT,
                                                       unsigned short* __restrict__ axb,
                                                       unsigned short* __restrict__ wb1,
                                                       unsigned short* __restrict__ wb2,
                                                       int N, int E, int nbucket,
                                                       int nbin, int xblocks) {
    __shared__ int hcnt[MAXB];
    int tid = threadIdx.x;
    int blk = blockIdx.x;
    if (blk < nbin) {               // ---- bhist role ----
        for (int t = tid; t < nbucket; t += 256) hcnt[t] = 0;
        __syncthreads();
        int e0 = blk * EPB;
        for (int it = 0; it < EPB / 256; ++it) {
            int e = e0 + it * 256 + tid;
            if (e < E) atomicAdd(&hcnt[ei[E + e] >> BSH], 1);
        }
        __syncthreads();
        for (int t = tid; t < nbucket; t += 256)
            histT[t * nbin + blk] = hcnt[t];
        return;
    }
    if (blk < nbin + xblocks) {     // ---- x conversion role ----
        int idx = (blk - nbin) * 256 + tid;
        if (idx >= N * 24) return;
        int n = idx / 24, q = idx - n * 24;
        float4 v = x4[idx];
        ushort4 o;
        o.x = f2bf(v.x); o.y = f2bf(v.y); o.z = f2bf(v.z); o.w = f2bf(v.w);
        *(ushort4*)(axb + (size_t)n * 192 + 96 + q * 4) = o;
        return;
    }
    // ---- weight conversion role ----
    int t = (blk - nbin - xblocks) * 256 + tid;    // 0 .. 51*64
    const float* src;
    unsigned short* dst;
    if (t < 36 * 64) {          // layer 1: Wcat=[W1l|W1r], 36 slots (kc*6+jt)
        int s = t >> 6, lane = t & 63;
        int kc = s / 6, jt = s - kc * 6;
        int j  = jt * 16 + (lane & 15);
        int k2 = kc * 32 + (lane >> 4) * 8;
        src = (k2 < 96) ? (W1l + j * 96 + k2) : (W1r + j * 96 + (k2 - 96));
        dst = wb1 + t * 8;
    } else if (t < 51 * 64) {   // layer 2: W2cat 80 rows, 15 slots (kc*5+jt)
        int t2 = t - 36 * 64;
        int s = t2 >> 6, lane = t2 & 63;
        int kc = s / 5, jt = s - kc * 5;
        int j  = jt * 16 + (lane & 15);
        int k2 = kc * 32 + (lane >> 4) * 8;
        src = (j < 40) ? (W2l + j * 96 + k2) : (W2r + (j - 40) * 96 + k2);
        dst = wb2 + t2 * 8;
    } else return;
    ushort4 o0, o1;
    o0.x = f2bf(src[0]); o0.y = f2bf(src[1]); o0.z = f2bf(src[2]); o0.w = f2bf(src[3]);
    o1.x = f2bf(src[4]); o1.y = f2bf(src[5]); o1.z = f2bf(src[6]); o1.w = f2bf(src[7]);
    *(ushort4*)(dst)     = o0;
    *(ushort4*)(dst + 4) = o1;
}

// ---------------------------------------------------------------------------
// CSR phase 1a: per-bucket exclusive scan over blocks (in place) + bucket
// total. No fences, no tickets.
// ---------------------------------------------------------------------------
__global__ __launch_bounds__(256) void bsum_kernel(int* __restrict__ histT,
                                                   int* __restrict__ gbh, int nbin) {
    __shared__ int s[256];
    int k = blockIdx.x, tid = threadIdx.x;
    int v = (tid < nbin) ? histT[k * nbin + tid] : 0;
    s[tid] = v;
    __syncthreads();
    for (int off = 1; off < 256; off <<= 1) {
        int o = (tid >= off) ? s[tid - off] : 0;
        __syncthreads();
        s[tid] += o;
        __syncthreads();
    }
    if (tid < nbin) histT[k * nbin + tid] = s[tid] - v;   // exclusive prefix
    if (tid == 255) gbh[k] = s[255];                      // bucket total
}

// ---------------------------------------------------------------------------
// CSR phase 1b: single-block exclusive scan of bucket totals -> gbase
// (256 threads x 4/thread, supports nbucket <= 1024); rp sentinel.
// ---------------------------------------------------------------------------
__global__ __launch_bounds__(256) void bscan_kernel(const int* __restrict__ gbh,
                                                    int* __restrict__ gbase,
                                                    int* __restrict__ rp,
                                                    int N, int E, int nbucket) {
    __shared__ int s[256];
    int tid  = threadIdx.x;
    int base = tid * 4;
    int w0 = (base     < nbucket) ? gbh[base]     : 0;
    int w1 = (base + 1 < nbucket) ? gbh[base + 1] : 0;
    int w2 = (base + 2 < nbucket) ? gbh[base + 2] : 0;
    int w3 = (base + 3 < nbucket) ? gbh[base + 3] : 0;
    int tsum = w0 + w1 + w2 + w3;
    s[tid] = tsum;
    __syncthreads();
    for (int off = 1; off < 256; off <<= 1) {
        int o = (tid >= off) ? s[tid - off] : 0;
        __syncthreads();
        s[tid] += o;
        __syncthreads();
    }
    int excl = s[tid] - tsum;
    if (base < nbucket) {
        gbase[base] = excl;
        if (base + 1 <= nbucket) gbase[base + 1] = excl + w0;
        if (base + 2 <= nbucket) gbase[base + 2] = excl + w0 + w1;
        if (base + 3 <= nbucket) gbase[base + 3] = excl + w0 + w1 + w2;
    }
    if (tid == 0) { gbase[nbucket] = E; rp[N] = E; }
}

// ---------------------------------------------------------------------------
// CSR phase 2: deterministic single-pass bin. base = gbase[b] +
// histT[b][blk]; LDS cursors. tmp packs src (16b) | local-dst (7b) << 16.
// ---------------------------------------------------------------------------
__global__ __launch_bounds__(256) void bin_kernel(const int* __restrict__ ei,
                                                  const int* __restrict__ gbase,
                                                  const int* __restrict__ histT,
                                                  unsigned int* __restrict__ tmp,
                                                  int E, int nbucket, int nbin) {
    __shared__ int lcnt[MAXB];
    __shared__ int lbase[MAXB];
    int tid = threadIdx.x;
    for (int t = tid; t < nbucket; t += 256) {
        lbase[t] = gbase[t] + histT[t * nbin + blockIdx.x];
        lcnt[t]  = 0;
    }
    __syncthreads();
    int e0 = blockIdx.x * EPB;
    for (int it = 0; it < EPB / 256; ++it) {
        int e = e0 + it * 256 + tid;
        if (e < E) {
            int src = ei[e], dst = ei[E + e];
            int b   = dst >> BSH;
            int ofs = atomicAdd(&lcnt[b], 1);
            tmp[lbase[b] + ofs] = (unsigned)src | ((unsigned)(dst & (BSIZE - 1)) << 16);
        }
    }
}

// ---------------------------------------------------------------------------
// CSR phase 3: one block per 128-node bucket -> exact rp + u16 col.
// (Aggregation un-fused: the gather needs a big grid, this kernel doesn't.)
// ---------------------------------------------------------------------------
__global__ __launch_bounds__(256) void csr_fin_kernel(const unsigned int* __restrict__ tmp,
                                                      const int* __restrict__ gbase,
                                                      int* __restrict__ rp,
                                                      unsigned short* __restrict__ col,
                                                      int N) {
    __shared__ int ncnt[BSIZE], nofs[BSIZE], sscan[BSIZE];
    int b   = blockIdx.x;
    int tid = threadIdx.x;
    int s0 = gbase[b], s1 = gbase[b + 1];
    if (tid < BSIZE) ncnt[tid] = 0;
    __syncthreads();
    for (int i = s0 + tid; i < s1; i += 256)
        atomicAdd(&ncnt[tmp[i] >> 16], 1);
    __syncthreads();
    int v = (tid < BSIZE) ? ncnt[tid] : 0;
    if (tid < BSIZE) sscan[tid] = v;
    __syncthreads();
    for (int off = 1; off < BSIZE; off <<= 1) {
        int o = (tid < BSIZE && tid >= off) ? sscan[tid - off] : 0;
        __syncthreads();
        if (tid < BSIZE) sscan[tid] += o;
        __syncthreads();
    }
    if (tid < BSIZE) {
        nofs[tid] = sscan[tid] - v;       // exclusive prefix (local)
        int node = (b << BSH) + tid;
        if (node < N) rp[node] = s0 + nofs[tid];
        ncnt[tid] = 0;
    }
    __syncthreads();
    for (int i = s0 + tid; i < s1; i += 256) {
        unsigned int t2 = tmp[i];
        int d   = t2 >> 16;
        int ofs = atomicAdd(&ncnt[d], 1);
        col[s0 + nofs[d] + ofs] = (unsigned short)(t2 & 0xffffu);
    }
}

// ---------------------------------------------------------------------------
// Layer-1 aggregation (standalone, high occupancy): thread = (node, 16B
// chunk), grid ~2346 blocks. 8-edge unroll for outstanding-load depth.
// ---------------------------------------------------------------------------
__global__ __launch_bounds__(256) void agg_kernel(const int* __restrict__ rp,
                                                  const unsigned short* __restrict__ col,
                                                  unsigned short* __restrict__ axb,
                                                  int N) {
    int idx = blockIdx.x * 256 + threadIdx.x;
    if (idx >= N * 12) return;
    int n = idx / 12, q = idx - n * 12;
    int s = rp[n], e = rp[n + 1];
    float a0=0.f,a1=0.f,a2=0.f,a3=0.f,a4=0.f,a5=0.f,a6=0.f,a7=0.f;
    int i = s;
    for (; i + 7 < e; i += 8) {
        #pragma unroll
        for (int u = 0; u < 8; ++u) {
            int c = col[i + u];
            uint4 w = *(const uint4*)(axb + (size_t)c * 192 + 96 + q * 8);
            a0 += bf2f(w.x & 0xffffu); a1 += bf2f(w.x >> 16);
            a2 += bf2f(w.y & 0xffffu); a3 += bf2f(w.y >> 16);
            a4 += bf2f(w.z & 0xffffu); a5 += bf2f(w.z >> 16);
            a6 += bf2f(w.w & 0xffffu); a7 += bf2f(w.w >> 16);
        }
    }
    for (; i < e; ++i) {
        int c = col[i];
        uint4 w = *(const uint4*)(axb + (size_t)c * 192 + 96 + q * 8);
        a0 += bf2f(w.x & 0xffffu); a1 += bf2f(w.x >> 16);
        a2 += bf2f(w.y & 0xffffu); a3 += bf2f(w.y >> 16);
        a4 += bf2f(w.z & 0xffffu); a5 += bf2f(w.z >> 16);
        a6 += bf2f(w.w & 0xffffu); a7 += bf2f(w.w >> 16);
    }
    int deg = e - s;
    float inv = 1.0f / (float)(deg > 1 ? deg : 1);
    ushort4 o0, o1;
    o0.x = f2bf(a0 * inv); o0.y = f2bf(a1 * inv);
    o0.z = f2bf(a2 * inv); o0.w = f2bf(a3 * inv);
    o1.x = f2bf(a4 * inv); o1.y = f2bf(a5 * inv);
    o1.z = f2bf(a6 * inv); o1.w = f2bf(a7 * inv);
    *(ushort4*)(axb + (size_t)n * 192 + q * 8)     = o0;
    *(ushort4*)(axb + (size_t)n * 192 + q * 8 + 4) = o1;
}

// ---------------------------------------------------------------------------
// Fused layer-1 GEMM + layer-2 projection. h stays in LDS; b2 folded into pr.
// ---------------------------------------------------------------------------
__global__ __launch_bounds__(256) void l1proj_kernel(const unsigned short* __restrict__ axb,
                                                     const unsigned short* __restrict__ wb1,
                                                     const float* __restrict__ b1,
                                                     const unsigned short* __restrict__ wb2,
                                                     const float* __restrict__ b2,
                                                     unsigned short* __restrict__ pl,
                                                     float* __restrict__ pr,
                                                     int N) {
    __shared__ unsigned short sh[128 * 104];
    int wave = threadIdx.x >> 6, lane = threadIdx.x & 63;
    int nbase = blockIdx.x * 128 + wave * 32;    // global node base of wave
    int lbase = wave * 32;                       // local node base of wave
    int mrow = lane & 15, quad = lane >> 4;

    {   // ---- phase 1: L1 MFMA ----
        float4v acc[2][6] = {};
        const short8* W = (const short8*)wb1;
        #pragma unroll
        for (int kc = 0; kc < 6; ++kc) {
            short8 a0 = *(const short8*)(axb + (size_t)(nbase + mrow)      * 192 + kc * 32 + quad * 8);
            short8 a1 = *(const short8*)(axb + (size_t)(nbase + 16 + mrow) * 192 + kc * 32 + quad * 8);
            #pragma unroll
            for (int jt = 0; jt < 6; ++jt) {
                short8 b = W[(kc * 6 + jt) * 64 + lane];
                acc[0][jt] = __builtin_amdgcn_mfma_f32_16x16x32_bf16(a0, b, acc[0][jt], 0, 0, 0);
                acc[1][jt] = __builtin_amdgcn_mfma_f32_16x16x32_bf16(a1, b, acc[1][jt], 0, 0, 0);
            }
        }
        #pragma unroll
        for (int jt = 0; jt < 6; ++jt) {
            int j = jt * 16 + mrow;
            float bj = b1[j];
            #pragma unroll
            for (int mt = 0; mt < 2; ++mt) {
                #pragma unroll
                for (int r = 0; r < 4; ++r) {
                    int nl = lbase + mt * 16 + quad * 4 + r;
                    sh[nl * 104 + j] = f2bf(fmaxf(acc[mt][jt][r] + bj, 0.f));
                }
            }
        }
    }
    __syncthreads();
    {   // ---- phase 2: projection MFMA from LDS ----
        float4v acc[2][5] = {};
        const short8* W = (const short8*)wb2;
        #pragma unroll
        for (int kc = 0; kc < 3; ++kc) {
            short8 a0 = *(const short8*)&sh[(lbase + mrow)      * 104 + kc * 32 + quad * 8];
            short8 a1 = *(const short8*)&sh[(lbase + 16 + mrow) * 104 + kc * 32 + quad * 8];
            #pragma unroll
            for (int jt = 0; jt < 5; ++jt) {
                short8 b = W[(kc * 5 + jt) * 64 + lane];
                acc[0][jt] = __builtin_amdgcn_mfma_f32_16x16x32_bf16(a0, b, acc[0][jt], 0, 0, 0);
                acc[1][jt] = __builtin_amdgcn_mfma_f32_16x16x32_bf16(a1, b, acc[1][jt], 0, 0, 0);
            }
        }
        #pragma unroll
        for (int jt = 0; jt < 5; ++jt) {
            int j = jt * 16 + mrow;
            float b2v = (j >= 40) ? b2[j - 40] : 0.f;
            #pragma unroll
            for (int mt = 0; mt < 2; ++mt) {
                #pragma unroll
                for (int r = 0; r < 4; ++r) {
                    int node = nbase + mt * 16 + quad * 4 + r;
                    if (node < N) {
                        float v = acc[mt][jt][r];
                        if (j < 40) pl[(size_t)node * 64 + j] = f2bf(v);
                        else        pr[(size_t)node * 40 + (j - 40)] = v + b2v;
                    }
                }
            }
        }
    }
}

// ---------------------------------------------------------------------------
// Final: logits = mean_{src}(pl[src]) + pr[n] (b2 pre-folded); log_softmax.
// One wave per node; lane (g,c): 6 edges x 4-class uint2 loads per inst.
// ---------------------------------------------------------------------------
__global__ __launch_bounds__(256) void final_kernel(const unsigned short* __restrict__ pl,
                                                    const float* __restrict__ pr,
                                                    const int* __restrict__ rp,
                                                    const unsigned short* __restrict__ col,
                                                    float* __restrict__ out, int N) {
    __shared__ float red[4][6][40];
    int wave = threadIdx.x >> 6;
    int lane = threadIdx.x & 63;
    int n = blockIdx.x * 4 + wave;
    if (n >= N) return;
    int s = rp[n], e = rp[n + 1];
    int g = lane / 10;            // edge slot 0..5 (g==6 for lanes 60..63: idle)
    int c = lane - g * 10;        // class chunk: classes 4c..4c+3
    bool gok = (g < 6);
    float a0 = 0.f, a1 = 0.f, a2 = 0.f, a3 = 0.f;
    for (int base = s; base < e; base += 6) {
        int idx = base + g;
        if (gok && idx < e) {
            int cn = col[idx];
            uint2 u = *(const uint2*)(pl + (size_t)cn * 64 + c * 4);
            a0 += bf2f(u.x & 0xffffu); a1 += bf2f(u.x >> 16);
            a2 += bf2f(u.y & 0xffffu); a3 += bf2f(u.y >> 16);
        }
    }
    if (gok) {
        float4 t; t.x = a0; t.y = a1; t.z = a2; t.w = a3;
        *(float4*)&red[wave][g][c * 4] = t;
    }
    bool act = (lane < NCLASS);
    float v = -INFINITY;
    if (act) {
        float val = 0.f;
        #pragma unroll
        for (int gg = 0; gg < 6; ++gg) val += red[wave][gg][lane];
        int deg = e - s;
        float inv = 1.0f / (float)(deg > 1 ? deg : 1);
        v = val * inv + pr[(size_t)n * 40 + lane];
    }
    float m = v;
    #pragma unroll
    for (int off = 32; off >= 1; off >>= 1) m = fmaxf(m, __shfl_xor(m, off));
    float ex = act ? __expf(v - m) : 0.f;
    float ssum = ex;
    #pragma unroll
    for (int off = 32; off >= 1; off >>= 1) ssum += __shfl_xor(ssum, off);
    if (act) out[(size_t)n * 40 + lane] = v - m - __logf(ssum);
}

// ---------------------------------------------------------------------------
// Host launcher: 8 dispatches.
// ---------------------------------------------------------------------------
extern "C" void kernel_launch(void* const* d_in, const int* in_sizes, int n_in,
                              void* d_out, int out_size, void* d_ws, size_t ws_size,
                              hipStream_t stream) {
    const float* x   = (const float*)d_in[0];
    const int*   ei  = (const int*)  d_in[1];
    const float* W1l = (const float*)d_in[2];
    const float* b1  = (const float*)d_in[3];
    const float* W1r = (const float*)d_in[4];
    const float* W2l = (const float*)d_in[5];
    const float* b2  = (const float*)d_in[6];
    const float* W2r = (const float*)d_in[7];
    float* out = (float*)d_out;

    const int N = in_sizes[0] / 96;        // 50000 (< 65536 for u16 col)
    const int E = in_sizes[1] / 2;         // 800000
    const int nbucket = (N + BSIZE - 1) >> BSH;   // 391 (<= MAXB)
    const int nbin = (E + EPB - 1) / EPB;  // 196 (<= 256)
    const int NB   = (N + 127) / 128;      // 391 l1proj blocks
    const int NP2  = NB * 128;             // padded rows (= nbucket*128)
    const int xblocks = (N * 24 + 255) / 256;

    // Workspace layout (all offsets 256-aligned).
    auto al = [](size_t v) { return (v + 255) & ~(size_t)255; };
    char* ws = (char*)d_ws;
    size_t o = 0;
    int* histT = (int*)(ws + o); o = al(o + (size_t)MAXB * 256 * 4);
    int* gbh   = (int*)(ws + o); o = al(o + (size_t)MAXB * 4);
    int* gbase = (int*)(ws + o); o = al(o + (size_t)(MAXB + 1) * 4);
    int* rp    = (int*)(ws + o); o = al(o + (size_t)(N + 1) * 4);
    unsigned int*   tmp = (unsigned int*)(ws + o);   o = al(o + (size_t)E * 4);
    unsigned short* col = (unsigned short*)(ws + o); o = al(o + (size_t)E * 2);
    unsigned short* axb = (unsigned short*)(ws + o); o = al(o + (size_t)NP2 * 192 * 2);
    unsigned short* wb1 = (unsigned short*)(ws + o); o = al(o + 36 * 64 * 8 * 2);
    unsigned short* wb2 = (unsigned short*)(ws + o); o = al(o + 15 * 64 * 8 * 2);
    unsigned short* pl  = (unsigned short*)(ws + o); o = al(o + (size_t)NP2 * 64 * 2);
    float*          pr  = (float*)(ws + o);          o = al(o + (size_t)N * 40 * 4);

    // 1. merged bhist + conversions
    convhist_kernel<<<nbin + xblocks + 13, 256, 0, stream>>>(
        ei, (const float4*)x, W1l, W1r, W2l, W2r, histT, axb, wb1, wb2,
        N, E, nbucket, nbin, xblocks);
    // 2-4. CSR build
    bsum_kernel <<<nbucket, 256, 0, stream>>>(histT, gbh, nbin);
    bscan_kernel<<<1, 256, 0, stream>>>(gbh, gbase, rp, N, E, nbucket);
    bin_kernel  <<<nbin, 256, 0, stream>>>(ei, gbase, histT, tmp, E, nbucket, nbin);
    // 5. CSR finalize (rp + col)
    csr_fin_kernel<<<nbucket, 256, 0, stream>>>(tmp, gbase, rp, col, N);
    // 6. layer-1 gather-mean at full occupancy
    agg_kernel<<<(N * 12 + 255) / 256, 256, 0, stream>>>(rp, col, axb, N);
    // 7. fused L1 GEMM + L2 projection (h stays in LDS; b2 folded into pr)
    l1proj_kernel<<<NB, 256, 0, stream>>>(axb, wb1, b1, wb2, b2, pl, pr, N);
    // 8. aggregate 40-dim + log_softmax
    final_kernel<<<(N + 3) / 4, 256, 0, stream>>>(pl, pr, rp, col, out, N);
}

// Round 11
// 171.258 us; speedup vs baseline: 1.0653x; 1.0653x over previous
//
#include <hip/hip_runtime.h>
#include <hip/hip_fp8.h>
#include <math.h>

#define NCLASS 40
#define BSH    6        // bucket = dst>>6 (64 nodes/bucket)
#define BSIZE  64
#define MAXB   1024     // max buckets; N=50000 -> 782 used
#define EPB    4096     // edges per block in bhist/bin (E<=1M -> nbin<=256)
#define LCOL   2048     // LDS col capacity per bucket (mean 1024, sd ~32)

typedef __attribute__((ext_vector_type(8))) short short8;   // 8 bf16 = 4 VGPRs
typedef __attribute__((ext_vector_type(4))) float float4v;  // MFMA 16x16 C/D

__device__ __forceinline__ unsigned short f2bf(float f) {
    union { float f; unsigned u; } v; v.f = f;
    unsigned r = v.u + 0x7fffu + ((v.u >> 16) & 1u);   // round-nearest-even
    return (unsigned short)(r >> 16);
}
__device__ __forceinline__ float bf2f(unsigned int s) {
    union { unsigned u; float f; } v; v.u = s << 16; return v.f;
}
// decode 4 OCP-e4m3 bytes of one dword, accumulate into a[0..3]
__device__ __forceinline__ void acc_fp8x4(unsigned int v, float* a) {
    #pragma unroll
    for (int k = 0; k < 4; ++k) {
        __hip_fp8_e4m3 q8; q8.__x = (__hip_fp8_storage_t)((v >> (8 * k)) & 0xffu);
        a[k] += (float)q8;
    }
}

// ---------------------------------------------------------------------------
// Merged: bhist (blocks [0,nbin)) + x->bf16/fp8 conv + W1/W2 frag-order conv.
// x is written twice: bf16 into axb x-half (exact path for x@W1r^T) and fp8
// e4m3 into xq (gather source; 128B rows = ONE cacheline per edge gather).
// ---------------------------------------------------------------------------
__global__ __launch_bounds__(256) void convhist_kernel(const int* __restrict__ ei,
                                                       const float4* __restrict__ x4,
                                                       const float* __restrict__ W1l,
                                                       const float* __restrict__ W1r,
                                                       const float* __restrict__ W2l,
                                                       const float* __restrict__ W2r,
                                                       int* __restrict__ histT,
                                                       unsigned short* __restrict__ axb,
                                                       unsigned char* __restrict__ xq,
                                                       unsigned short* __restrict__ wb1,
                                                       unsigned short* __restrict__ wb2,
                                                       int N, int E, int nbucket,
                                                       int nbin, int xblocks) {
    __shared__ int hcnt[MAXB];
    int tid = threadIdx.x;
    int blk = blockIdx.x;
    if (blk < nbin) {               // ---- bhist role ----
        for (int t = tid; t < nbucket; t += 256) hcnt[t] = 0;
        __syncthreads();
        int e0 = blk * EPB;
        for (int it = 0; it < EPB / 256; ++it) {
            int e = e0 + it * 256 + tid;
            if (e < E) atomicAdd(&hcnt[ei[E + e] >> BSH], 1);
        }
        __syncthreads();
        for (int t = tid; t < nbucket; t += 256)
            histT[t * nbin + blk] = hcnt[t];
        return;
    }
    if (blk < nbin + xblocks) {     // ---- x conversion role ----
        int idx = (blk - nbin) * 256 + tid;
        if (idx >= N * 24) return;
        int n = idx / 24, q = idx - n * 24;
        float4 v = x4[idx];
        ushort4 o;
        o.x = f2bf(v.x); o.y = f2bf(v.y); o.z = f2bf(v.z); o.w = f2bf(v.w);
        *(ushort4*)(axb + (size_t)n * 192 + 96 + q * 4) = o;
        __hip_fp8_e4m3 q0(v.x), q1(v.y), q2(v.z), q3(v.w);
        unsigned int pk = (unsigned)q0.__x | ((unsigned)q1.__x << 8)
                        | ((unsigned)q2.__x << 16) | ((unsigned)q3.__x << 24);
        *(unsigned int*)(xq + (size_t)n * 128 + q * 4) = pk;
        return;
    }
    // ---- weight conversion role ----
    int t = (blk - nbin - xblocks) * 256 + tid;    // 0 .. 51*64
    const float* src;
    unsigned short* dst;
    if (t < 36 * 64) {          // layer 1: Wcat=[W1l|W1r], 36 slots (kc*6+jt)
        int s = t >> 6, lane = t & 63;
        int kc = s / 6, jt = s - kc * 6;
        int j  = jt * 16 + (lane & 15);
        int k2 = kc * 32 + (lane >> 4) * 8;
        src = (k2 < 96) ? (W1l + j * 96 + k2) : (W1r + j * 96 + (k2 - 96));
        dst = wb1 + t * 8;
    } else if (t < 51 * 64) {   // layer 2: W2cat 80 rows, 15 slots (kc*5+jt)
        int t2 = t - 36 * 64;
        int s = t2 >> 6, lane = t2 & 63;
        int kc = s / 5, jt = s - kc * 5;
        int j  = jt * 16 + (lane & 15);
        int k2 = kc * 32 + (lane >> 4) * 8;
        src = (j < 40) ? (W2l + j * 96 + k2) : (W2r + (j - 40) * 96 + k2);
        dst = wb2 + t2 * 8;
    } else return;
    ushort4 o0, o1;
    o0.x = f2bf(src[0]); o0.y = f2bf(src[1]); o0.z = f2bf(src[2]); o0.w = f2bf(src[3]);
    o1.x = f2bf(src[4]); o1.y = f2bf(src[5]); o1.z = f2bf(src[6]); o1.w = f2bf(src[7]);
    *(ushort4*)(dst)     = o0;
    *(ushort4*)(dst + 4) = o1;
}

// ---------------------------------------------------------------------------
// CSR phase 1a: per-bucket exclusive scan over blocks (in place) + bucket
// total. No fences, no tickets.
// ---------------------------------------------------------------------------
__global__ __launch_bounds__(256) void bsum_kernel(int* __restrict__ histT,
                                                   int* __restrict__ gbh, int nbin) {
    __shared__ int s[256];
    int k = blockIdx.x, tid = threadIdx.x;
    int v = (tid < nbin) ? histT[k * nbin + tid] : 0;
    s[tid] = v;
    __syncthreads();
    for (int off = 1; off < 256; off <<= 1) {
        int o = (tid >= off) ? s[tid - off] : 0;
        __syncthreads();
        s[tid] += o;
        __syncthreads();
    }
    if (tid < nbin) histT[k * nbin + tid] = s[tid] - v;   // exclusive prefix
    if (tid == 255) gbh[k] = s[255];                      // bucket total
}

// ---------------------------------------------------------------------------
// CSR phase 1b: single-block exclusive scan of bucket totals -> gbase
// (256 threads x 4/thread, supports nbucket <= 1024); rp sentinel.
// ---------------------------------------------------------------------------
__global__ __launch_bounds__(256) void bscan_kernel(const int* __restrict__ gbh,
                                                    int* __restrict__ gbase,
                                                    int* __restrict__ rp,
                                                    int N, int E, int nbucket) {
    __shared__ int s[256];
    int tid  = threadIdx.x;
    int base = tid * 4;
    int w0 = (base     < nbucket) ? gbh[base]     : 0;
    int w1 = (base + 1 < nbucket) ? gbh[base + 1] : 0;
    int w2 = (base + 2 < nbucket) ? gbh[base + 2] : 0;
    int w3 = (base + 3 < nbucket) ? gbh[base + 3] : 0;
    int tsum = w0 + w1 + w2 + w3;
    s[tid] = tsum;
    __syncthreads();
    for (int off = 1; off < 256; off <<= 1) {
        int o = (tid >= off) ? s[tid - off] : 0;
        __syncthreads();
        s[tid] += o;
        __syncthreads();
    }
    int excl = s[tid] - tsum;
    if (base < nbucket) {
        gbase[base] = excl;
        if (base + 1 <= nbucket) gbase[base + 1] = excl + w0;
        if (base + 2 <= nbucket) gbase[base + 2] = excl + w0 + w1;
        if (base + 3 <= nbucket) gbase[base + 3] = excl + w0 + w1 + w2;
    }
    if (tid == 0) { gbase[nbucket] = E; rp[N] = E; }
}

// ---------------------------------------------------------------------------
// CSR phase 2: deterministic single-pass bin. base = gbase[b] +
// histT[b][blk]; LDS cursors. tmp packs src (16b) | local-dst (6b) << 16.
// ---------------------------------------------------------------------------
__global__ __launch_bounds__(256) void bin_kernel(const int* __restrict__ ei,
                                                  const int* __restrict__ gbase,
                                                  const int* __restrict__ histT,
                                                  unsigned int* __restrict__ tmp,
                                                  int E, int nbucket, int nbin) {
    __shared__ int lcnt[MAXB];
    __shared__ int lbase[MAXB];
    int tid = threadIdx.x;
    for (int t = tid; t < nbucket; t += 256) {
        lbase[t] = gbase[t] + histT[t * nbin + blockIdx.x];
        lcnt[t]  = 0;
    }
    __syncthreads();
    int e0 = blockIdx.x * EPB;
    for (int it = 0; it < EPB / 256; ++it) {
        int e = e0 + it * 256 + tid;
        if (e < E) {
            int src = ei[e], dst = ei[E + e];
            int b   = dst >> BSH;
            int ofs = atomicAdd(&lcnt[b], 1);
            tmp[lbase[b] + ofs] = (unsigned)src | ((unsigned)(dst & (BSIZE - 1)) << 16);
        }
    }
}

// ---------------------------------------------------------------------------
// CSR phase 3 + layer-1 aggregation, fused. One block per 64-node bucket.
// Gather source is fp8 xq (ONE 128B line per edge); fp32 accumulate; bf16
// write into axb agg-half (l1proj unchanged).
// ---------------------------------------------------------------------------
__global__ __launch_bounds__(256) void csr_agg_kernel(const unsigned int* __restrict__ tmp,
                                                      const int* __restrict__ gbase,
                                                      int* __restrict__ rp,
                                                      unsigned short* __restrict__ col,
                                                      const unsigned char* __restrict__ xq,
                                                      unsigned short* __restrict__ axb,
                                                      int N) {
    __shared__ int ncnt[BSIZE], nofs[BSIZE], sscan[BSIZE];
    __shared__ unsigned short lcol[LCOL];
    int b   = blockIdx.x;
    int tid = threadIdx.x;
    int s0 = gbase[b], s1 = gbase[b + 1];
    int cnt = s1 - s0;
    bool inl = (cnt <= LCOL);
    if (tid < BSIZE) ncnt[tid] = 0;
    __syncthreads();
    for (int i = s0 + tid; i < s1; i += 256)
        atomicAdd(&ncnt[tmp[i] >> 16], 1);
    __syncthreads();
    int v = (tid < BSIZE) ? ncnt[tid] : 0;
    if (tid < BSIZE) sscan[tid] = v;
    __syncthreads();
    for (int off = 1; off < BSIZE; off <<= 1) {
        int o = (tid < BSIZE && tid >= off) ? sscan[tid - off] : 0;
        __syncthreads();
        if (tid < BSIZE) sscan[tid] += o;
        __syncthreads();
    }
    if (tid < BSIZE) {
        nofs[tid] = sscan[tid] - v;       // exclusive prefix (local)
        int node = (b << BSH) + tid;
        if (node < N) rp[node] = s0 + nofs[tid];
        ncnt[tid] = 0;
    }
    __syncthreads();
    for (int i = s0 + tid; i < s1; i += 256) {
        unsigned int t2 = tmp[i];
        int d   = t2 >> 16;
        int ofs = atomicAdd(&ncnt[d], 1);
        int pos = nofs[d] + ofs;
        unsigned short sv = (unsigned short)(t2 & 0xffffu);
        col[s0 + pos] = sv;               // global copy (consumed by final)
        if (inl) lcol[pos] = sv;
    }
    __syncthreads();
    // aggregation: 64 nodes x 6 chunks of 16 fp8 (16B); ncnt[nl] = degree.
    int nodebase = b << BSH;
    auto gather = [&](auto getc) {
        for (int item = tid; item < BSIZE * 6; item += 256) {
            int nl = item / 6;
            int q  = item - nl * 6;
            int ls  = nofs[nl];
            int deg = ncnt[nl];
            int le  = ls + deg;
            float a[16];
            #pragma unroll
            for (int k = 0; k < 16; ++k) a[k] = 0.f;
            int i = ls;
            for (; i + 3 < le; i += 4) {
                #pragma unroll
                for (int u = 0; u < 4; ++u) {
                    int c = getc(i + u);
                    uint4 w = *(const uint4*)(xq + (size_t)c * 128 + q * 16);
                    acc_fp8x4(w.x, a);
                    acc_fp8x4(w.y, a + 4);
                    acc_fp8x4(w.z, a + 8);
                    acc_fp8x4(w.w, a + 12);
                }
            }
            for (; i < le; ++i) {
                int c = getc(i);
                uint4 w = *(const uint4*)(xq + (size_t)c * 128 + q * 16);
                acc_fp8x4(w.x, a);
                acc_fp8x4(w.y, a + 4);
                acc_fp8x4(w.z, a + 8);
                acc_fp8x4(w.w, a + 12);
            }
            float inv = 1.0f / (float)(deg > 1 ? deg : 1);
            ushort4 o0, o1, o2, o3;
            o0.x = f2bf(a[0] * inv);  o0.y = f2bf(a[1] * inv);
            o0.z = f2bf(a[2] * inv);  o0.w = f2bf(a[3] * inv);
            o1.x = f2bf(a[4] * inv);  o1.y = f2bf(a[5] * inv);
            o1.z = f2bf(a[6] * inv);  o1.w = f2bf(a[7] * inv);
            o2.x = f2bf(a[8] * inv);  o2.y = f2bf(a[9] * inv);
            o2.z = f2bf(a[10] * inv); o2.w = f2bf(a[11] * inv);
            o3.x = f2bf(a[12] * inv); o3.y = f2bf(a[13] * inv);
            o3.z = f2bf(a[14] * inv); o3.w = f2bf(a[15] * inv);
            unsigned short* dst = axb + (size_t)(nodebase + nl) * 192 + q * 16;
            *(ushort4*)(dst)      = o0;
            *(ushort4*)(dst + 4)  = o1;
            *(ushort4*)(dst + 8)  = o2;
            *(ushort4*)(dst + 12) = o3;
        }
    };
    if (inl) gather([&](int i) { return (int)lcol[i]; });
    else     gather([&](int i) { return (int)col[s0 + i]; });
}

// ---------------------------------------------------------------------------
// Fused layer-1 GEMM + layer-2 projection. h stays in LDS; b2 folded into pr.
// ---------------------------------------------------------------------------
__global__ __launch_bounds__(256) void l1proj_kernel(const unsigned short* __restrict__ axb,
                                                     const unsigned short* __restrict__ wb1,
                                                     const float* __restrict__ b1,
                                                     const unsigned short* __restrict__ wb2,
                                                     const float* __restrict__ b2,
                                                     unsigned short* __restrict__ pl,
                                                     float* __restrict__ pr,
                                                     int N) {
    __shared__ unsigned short sh[128 * 104];
    int wave = threadIdx.x >> 6, lane = threadIdx.x & 63;
    int nbase = blockIdx.x * 128 + wave * 32;    // global node base of wave
    int lbase = wave * 32;                       // local node base of wave
    int mrow = lane & 15, quad = lane >> 4;

    {   // ---- phase 1: L1 MFMA ----
        float4v acc[2][6] = {};
        const short8* W = (const short8*)wb1;
        #pragma unroll
        for (int kc = 0; kc < 6; ++kc) {
            short8 a0 = *(const short8*)(axb + (size_t)(nbase + mrow)      * 192 + kc * 32 + quad * 8);
            short8 a1 = *(const short8*)(axb + (size_t)(nbase + 16 + mrow) * 192 + kc * 32 + quad * 8);
            #pragma unroll
            for (int jt = 0; jt < 6; ++jt) {
                short8 b = W[(kc * 6 + jt) * 64 + lane];
                acc[0][jt] = __builtin_amdgcn_mfma_f32_16x16x32_bf16(a0, b, acc[0][jt], 0, 0, 0);
                acc[1][jt] = __builtin_amdgcn_mfma_f32_16x16x32_bf16(a1, b, acc[1][jt], 0, 0, 0);
            }
        }
        #pragma unroll
        for (int jt = 0; jt < 6; ++jt) {
            int j = jt * 16 + mrow;
            float bj = b1[j];
            #pragma unroll
            for (int mt = 0; mt < 2; ++mt) {
                #pragma unroll
                for (int r = 0; r < 4; ++r) {
                    int nl = lbase + mt * 16 + quad * 4 + r;
                    sh[nl * 104 + j] = f2bf(fmaxf(acc[mt][jt][r] + bj, 0.f));
                }
            }
        }
    }
    __syncthreads();
    {   // ---- phase 2: projection MFMA from LDS ----
        float4v acc[2][5] = {};
        const short8* W = (const short8*)wb2;
        #pragma unroll
        for (int kc = 0; kc < 3; ++kc) {
            short8 a0 = *(const short8*)&sh[(lbase + mrow)      * 104 + kc * 32 + quad * 8];
            short8 a1 = *(const short8*)&sh[(lbase + 16 + mrow) * 104 + kc * 32 + quad * 8];
            #pragma unroll
            for (int jt = 0; jt < 5; ++jt) {
                short8 b = W[(kc * 5 + jt) * 64 + lane];
                acc[0][jt] = __builtin_amdgcn_mfma_f32_16x16x32_bf16(a0, b, acc[0][jt], 0, 0, 0);
                acc[1][jt] = __builtin_amdgcn_mfma_f32_16x16x32_bf16(a1, b, acc[1][jt], 0, 0, 0);
            }
        }
        #pragma unroll
        for (int jt = 0; jt < 5; ++jt) {
            int j = jt * 16 + mrow;
            float b2v = (j >= 40) ? b2[j - 40] : 0.f;
            #pragma unroll
            for (int mt = 0; mt < 2; ++mt) {
                #pragma unroll
                for (int r = 0; r < 4; ++r) {
                    int node = nbase + mt * 16 + quad * 4 + r;
                    if (node < N) {
                        float v = acc[mt][jt][r];
                        if (j < 40) pl[(size_t)node * 64 + j] = f2bf(v);
                        else        pr[(size_t)node * 40 + (j - 40)] = v + b2v;
                    }
                }
            }
        }
    }
}

// ---------------------------------------------------------------------------
// Final: logits = mean_{src}(pl[src]) + pr[n] (b2 pre-folded); log_softmax.
// One wave per node; lane (g,c): 6 edges x 4-class uint2 loads per inst.
// ---------------------------------------------------------------------------
__global__ __launch_bounds__(256) void final_kernel(const unsigned short* __restrict__ pl,
                                                    const float* __restrict__ pr,
                                                    const int* __restrict__ rp,
                                                    const unsigned short* __restrict__ col,
                                                    float* __restrict__ out, int N) {
    __shared__ float red[4][6][40];
    int wave = threadIdx.x >> 6;
    int lane = threadIdx.x & 63;
    int n = blockIdx.x * 4 + wave;
    if (n >= N) return;
    int s = rp[n], e = rp[n + 1];
    int g = lane / 10;            // edge slot 0..5 (g==6 for lanes 60..63: idle)
    int c = lane - g * 10;        // class chunk: classes 4c..4c+3
    bool gok = (g < 6);
    float a0 = 0.f, a1 = 0.f, a2 = 0.f, a3 = 0.f;
    for (int base = s; base < e; base += 6) {
        int idx = base + g;
        if (gok && idx < e) {
            int cn = col[idx];
            uint2 u = *(const uint2*)(pl + (size_t)cn * 64 + c * 4);
            a0 += bf2f(u.x & 0xffffu); a1 += bf2f(u.x >> 16);
            a2 += bf2f(u.y & 0xffffu); a3 += bf2f(u.y >> 16);
        }
    }
    if (gok) {
        float4 t; t.x = a0; t.y = a1; t.z = a2; t.w = a3;
        *(float4*)&red[wave][g][c * 4] = t;
    }
    bool act = (lane < NCLASS);
    float v = -INFINITY;
    if (act) {
        float val = 0.f;
        #pragma unroll
        for (int gg = 0; gg < 6; ++gg) val += red[wave][gg][lane];
        int deg = e - s;
        float inv = 1.0f / (float)(deg > 1 ? deg : 1);
        v = val * inv + pr[(size_t)n * 40 + lane];
    }
    float m = v;
    #pragma unroll
    for (int off = 32; off >= 1; off >>= 1) m = fmaxf(m, __shfl_xor(m, off));
    float ex = act ? __expf(v - m) : 0.f;
    float ssum = ex;
    #pragma unroll
    for (int off = 32; off >= 1; off >>= 1) ssum += __shfl_xor(ssum, off);
    if (act) out[(size_t)n * 40 + lane] = v - m - __logf(ssum);
}

// ---------------------------------------------------------------------------
// Host launcher: 7 dispatches.
// ---------------------------------------------------------------------------
extern "C" void kernel_launch(void* const* d_in, const int* in_sizes, int n_in,
                              void* d_out, int out_size, void* d_ws, size_t ws_size,
                              hipStream_t stream) {
    const float* x   = (const float*)d_in[0];
    const int*   ei  = (const int*)  d_in[1];
    const float* W1l = (const float*)d_in[2];
    const float* b1  = (const float*)d_in[3];
    const float* W1r = (const float*)d_in[4];
    const float* W2l = (const float*)d_in[5];
    const float* b2  = (const float*)d_in[6];
    const float* W2r = (const float*)d_in[7];
    float* out = (float*)d_out;

    const int N = in_sizes[0] / 96;        // 50000 (< 65536 for u16 col)
    const int E = in_sizes[1] / 2;         // 800000
    const int nbucket = (N + BSIZE - 1) >> BSH;   // 782 (<= MAXB)
    const int nbin = (E + EPB - 1) / EPB;  // 196 (<= 256)
    const int NB   = (N + 127) / 128;      // 391 l1proj blocks
    const int NP2  = NB * 128;             // padded rows (= nbucket*64)
    const int xblocks = (N * 24 + 255) / 256;

    // Workspace layout (all offsets 256-aligned).
    auto al = [](size_t v) { return (v + 255) & ~(size_t)255; };
    char* ws = (char*)d_ws;
    size_t o = 0;
    int* histT = (int*)(ws + o); o = al(o + (size_t)MAXB * 256 * 4);
    int* gbh   = (int*)(ws + o); o = al(o + (size_t)MAXB * 4);
    int* gbase = (int*)(ws + o); o = al(o + (size_t)(MAXB + 1) * 4);
    int* rp    = (int*)(ws + o); o = al(o + (size_t)(N + 1) * 4);
    unsigned int*   tmp = (unsigned int*)(ws + o);   o = al(o + (size_t)E * 4);
    unsigned short* col = (unsigned short*)(ws + o); o = al(o + (size_t)E * 2);
    unsigned short* axb = (unsigned short*)(ws + o); o = al(o + (size_t)NP2 * 192 * 2);
    unsigned char*  xq  = (unsigned char*)(ws + o);  o = al(o + (size_t)NP2 * 128);
    unsigned short* wb1 = (unsigned short*)(ws + o); o = al(o + 36 * 64 * 8 * 2);
    unsigned short* wb2 = (unsigned short*)(ws + o); o = al(o + 15 * 64 * 8 * 2);
    unsigned short* pl  = (unsigned short*)(ws + o); o = al(o + (size_t)NP2 * 64 * 2);
    float*          pr  = (float*)(ws + o);          o = al(o + (size_t)N * 40 * 4);

    // 1. merged bhist + conversions (bf16 + fp8 x copies, frag-order weights)
    convhist_kernel<<<nbin + xblocks + 13, 256, 0, stream>>>(
        ei, (const float4*)x, W1l, W1r, W2l, W2r, histT, axb, xq, wb1, wb2,
        N, E, nbucket, nbin, xblocks);
    // 2-4. CSR build
    bsum_kernel <<<nbucket, 256, 0, stream>>>(histT, gbh, nbin);
    bscan_kernel<<<1, 256, 0, stream>>>(gbh, gbase, rp, N, E, nbucket);
    bin_kernel  <<<nbin, 256, 0, stream>>>(ei, gbase, histT, tmp, E, nbucket, nbin);
    // 5. per-bucket CSR finalize + layer-1 gather-mean from fp8 (fused)
    csr_agg_kernel<<<nbucket, 256, 0, stream>>>(tmp, gbase, rp, col, xq, axb, N);
    // 6. fused L1 GEMM + L2 projection (h stays in LDS; b2 folded into pr)
    l1proj_kernel<<<NB, 256, 0, stream>>>(axb, wb1, b1, wb2, b2, pl, pr, N);
    // 7. aggregate 40-dim + log_softmax
    final_kernel<<<(N + 3) / 4, 256, 0, stream>>>(pl, pr, rp, col, out, N);
}